// Round 10
// baseline (384.156 us; speedup 1.0000x reference)
//
#include <hip/hip_runtime.h>
#include <hip/hip_bf16.h>
#include <math.h>

#define T_    3
#define RES_  24
#define DIM_  768
#define HEADS_ 16
#define DH_   48
#define EMB_  1024
#define HW_   576            // RES*RES
#define THW_  1728           // T*HW
#define MP_   1792           // THW padded to multiple of 128
#define MLP_  3072
#define NF_   5376           // 3*DIM + MLP
#define QKV_  2304           // 3*DIM
#define QK_   1536           // 2*DIM (q,k only)
#define KTOT_ 3840           // DIM + MLP (second GEMM K)
#define SPLITK_ 6
#define NCNT_ 168            // 14 m-tiles x 12 n-tiles
#define EPS_  1e-5f

typedef __attribute__((ext_vector_type(8))) short bf16x8;
typedef __attribute__((ext_vector_type(4))) float f32x4;

__device__ __forceinline__ float siluf(float x) { return x / (1.f + expf(-x)); }

__device__ __forceinline__ unsigned short f2bf(float f) {
    __hip_bfloat16 b = __float2bfloat16(f);
    return *reinterpret_cast<unsigned short*>(&b);
}

__device__ __forceinline__ float bf2f(unsigned short u) {
    return __uint_as_float(((unsigned)u) << 16);
}

__device__ __forceinline__ void async_copy16(const void* g, void* l) {
    __builtin_amdgcn_global_load_lds(
        (__attribute__((address_space(1))) void*)g,
        (__attribute__((address_space(3))) void*)l,
        16, 0, 0);
}

// ---------------------------------------------------------------------------
// K1: mod[t][j] = silu(emb[t]) @ w_mod + b_mod  (3x1536); also zeroes the
// gemm2 completion counters (always runs before gemm2 in-stream).
// ---------------------------------------------------------------------------
__global__ __launch_bounds__(256) void mod_kernel(
    const float* __restrict__ emb, const float* __restrict__ w_mod,
    const float* __restrict__ b_mod, float* __restrict__ mod,
    int* __restrict__ cnt)
{
    int t = blockIdx.y;
    int chunk = blockIdx.x;
    __shared__ float se[EMB_];
    __shared__ float part[128];
    int tid = threadIdx.x;
    if (blockIdx.x == 0 && blockIdx.y == 0 && tid < NCNT_) cnt[tid] = 0;
    for (int i = tid; i < EMB_; i += 256) {
        float e = emb[t * EMB_ + i];
        se[i] = e / (1.f + expf(-e));
    }
    __syncthreads();
    int r = tid >> 7;
    int c = tid & 127;
    int j = chunk * 128 + c;
    const float* wp = w_mod + j;
    float acc = 0.f;
    for (int e = r * 512; e < r * 512 + 512; ++e)
        acc += se[e] * wp[e * 1536];
    if (r == 1) part[c] = acc;
    __syncthreads();
    if (r == 0)
        mod[t * 1536 + j] = acc + part[c] + b_mod[j];
}

// ---------------------------------------------------------------------------
// K2: fused prep + LN — block-range partitioned (mod must already be done):
//   b in [0,4032):      W_fused (768x5376 f32) -> Bt1 (5376x768 bf16) transp.
//   b in [4032,6912):   [W_out;W_mlp] (3840x768) -> Bt2 (768x3840 bf16) tr.
//   b in [6912,7344):   ln_mod for 4 tokens each
// ---------------------------------------------------------------------------
__global__ __launch_bounds__(256) void prep_ln_kernel(
    const float* __restrict__ W_fused, unsigned short* __restrict__ Bt1,
    const float* __restrict__ W_out, const float* __restrict__ W_mlp,
    unsigned short* __restrict__ Bt2,
    const float* __restrict__ x, const float* __restrict__ mod,
    unsigned short* __restrict__ h)
{
    __shared__ float buf[1122];     // 32x33 tile (1056) or ln scratch
    int b = blockIdx.x;
    int tid = threadIdx.x;
    if (b < 4032) {
        float (*tile)[33] = (float(*)[33])buf;
        int n0 = (b % 168) * 32;
        int k0 = (b / 168) * 32;
        int c = tid & 31, r = tid >> 5;
#pragma unroll
        for (int i = 0; i < 4; ++i)
            tile[r + 8 * i][c] = W_fused[(size_t)(k0 + r + 8 * i) * NF_ + n0 + c];
        __syncthreads();
#pragma unroll
        for (int i = 0; i < 4; ++i)
            Bt1[(size_t)(n0 + r + 8 * i) * DIM_ + k0 + c] = f2bf(tile[c][r + 8 * i]);
    } else if (b < 6912) {
        int b2 = b - 4032;
        float (*tile)[33] = (float(*)[33])buf;
        int k0 = (b2 % 120) * 32;
        int n0 = (b2 / 120) * 32;
        int c = tid & 31, r = tid >> 5;
#pragma unroll
        for (int i = 0; i < 4; ++i) {
            int k = k0 + r + 8 * i;
            float v = (k < DIM_) ? W_out[(size_t)k * DIM_ + n0 + c]
                                 : W_mlp[(size_t)(k - DIM_) * DIM_ + n0 + c];
            tile[r + 8 * i][c] = v;
        }
        __syncthreads();
#pragma unroll
        for (int i = 0; i < 4; ++i)
            Bt2[(size_t)(n0 + r + 8 * i) * KTOT_ + k0 + c] = f2bf(tile[c][r + 8 * i]);
    } else {
        int m0 = (b - 6912) * 4;
        int t = m0 / HW_;
        int hw0 = m0 - t * HW_;
        const float* xp = x + (size_t)t * DIM_ * HW_ + hw0;
        float4 X0 = *(const float4*)(xp + (size_t)tid * HW_);
        float4 X1 = *(const float4*)(xp + (size_t)(tid + 256) * HW_);
        float4 X2 = *(const float4*)(xp + (size_t)(tid + 512) * HW_);
        float4 sv, sqv;
        sv.x = X0.x + X1.x + X2.x;  sv.y = X0.y + X1.y + X2.y;
        sv.z = X0.z + X1.z + X2.z;  sv.w = X0.w + X1.w + X2.w;
        sqv.x = X0.x*X0.x + X1.x*X1.x + X2.x*X2.x;
        sqv.y = X0.y*X0.y + X1.y*X1.y + X2.y*X2.y;
        sqv.z = X0.z*X0.z + X1.z*X1.z + X2.z*X2.z;
        sqv.w = X0.w*X0.w + X1.w*X1.w + X2.w*X2.w;
#pragma unroll
        for (int off = 32; off > 0; off >>= 1) {
            sv.x += __shfl_xor(sv.x, off, 64);  sv.y += __shfl_xor(sv.y, off, 64);
            sv.z += __shfl_xor(sv.z, off, 64);  sv.w += __shfl_xor(sv.w, off, 64);
            sqv.x += __shfl_xor(sqv.x, off, 64); sqv.y += __shfl_xor(sqv.y, off, 64);
            sqv.z += __shfl_xor(sqv.z, off, 64); sqv.w += __shfl_xor(sqv.w, off, 64);
        }
        float* ssum = buf;        // 16 floats
        float* ssq  = buf + 16;   // 16 floats
        int lane = tid & 63, wid = tid >> 6;
        if (lane == 0) {
            *(float4*)&ssum[wid * 4] = sv;
            *(float4*)&ssq[wid * 4] = sqv;
        }
        __syncthreads();
        float mean[4], rs[4];
#pragma unroll
        for (int j = 0; j < 4; ++j) {
            float tot  = ssum[j] + ssum[4 + j] + ssum[8 + j] + ssum[12 + j];
            float totq = ssq[j] + ssq[4 + j] + ssq[8 + j] + ssq[12 + j];
            float mn = tot * (1.f / 768.f);
            float var = totq * (1.f / 768.f) - mn * mn;
            mean[j] = mn;
            rs[j] = rsqrtf(var + EPS_);
        }
        const float* sc = mod + t * 1536;
        const float* sh = sc + 768;
#pragma unroll
        for (int cc = 0; cc < 3; ++cc) {
            int c = tid + cc * 256;
            float4 X = (cc == 0) ? X0 : (cc == 1) ? X1 : X2;
            float scl = 1.f + sc[c];
            float shf = sh[c];
            const float* Xp = (const float*)&X;
#pragma unroll
            for (int j = 0; j < 4; ++j)
                h[(size_t)(m0 + j) * DIM_ + c] =
                    f2bf((Xp[j] - mean[j]) * rs[j] * scl + shf);
        }
    }
}

// ---------------------------------------------------------------------------
// K3: MFMA GEMM1, 128x64 tile, double-buffered LDS, 1 barrier/iter.
// C = h(1792x768) @ Bt1^T(5376x768) + b_fused
// ---------------------------------------------------------------------------
__global__ __launch_bounds__(256) void gemm1_kernel(
    const unsigned short* __restrict__ A,   // 1792 x 768
    const unsigned short* __restrict__ Bt,  // 5376 x 768
    const float* __restrict__ bias,
    unsigned short* __restrict__ qkvb,      // 1728 x 1536 (q,k bf16)
    unsigned short* __restrict__ vb,        // 1728 x 768 (v, bf16)
    unsigned short* __restrict__ A2)        // 1792 x 3840
{
    const int K = DIM_;
    const int NI = K / 32;                  // 24
    __shared__ unsigned short As[2][128 * 32];
    __shared__ unsigned short Bs[2][64 * 32];
    int tid = threadIdx.x;
    int bm = blockIdx.y * 128;
    int bn = blockIdx.x * 64;
    int wave = tid >> 6, lane = tid & 63;
    int quad = lane >> 4, l16 = lane & 15;
    int wm = (wave & 1) * 64;
    int wn = (wave >> 1) * 32;
    f32x4 acc[4][2] = {};
    int arow0 = tid >> 2,             akoff0 = (tid & 3) * 8;
    int arow1 = (tid + 256) >> 2,     akoff1 = (tid & 3) * 8;
    int brow = tid >> 2,              bkoff = (tid & 3) * 8;
    const unsigned short* Ag0 = A + (size_t)(bm + arow0) * K + akoff0;
    const unsigned short* Ag1 = A + (size_t)(bm + arow1) * K + akoff1;
    const unsigned short* Bg  = Bt + (size_t)(bn + brow) * K + bkoff;
    int la0 = arow0 * 32 + akoff0;
    int la1 = arow1 * 32 + akoff1;
    int lb  = brow * 32 + bkoff;
    async_copy16(Ag0, &As[0][la0]);
    async_copy16(Ag1, &As[0][la1]);
    async_copy16(Bg,  &Bs[0][lb]);
    for (int i = 0; i < NI; ++i) {
        __syncthreads();
        if (i + 1 < NI) {
            int k0 = (i + 1) * 32;
            int b = (i + 1) & 1;
            async_copy16(Ag0 + k0, &As[b][la0]);
            async_copy16(Ag1 + k0, &As[b][la1]);
            async_copy16(Bg + k0,  &Bs[b][lb]);
        }
        int b = i & 1;
        bf16x8 af[4], bf[2];
#pragma unroll
        for (int mt = 0; mt < 4; ++mt)
            af[mt] = *(const bf16x8*)&As[b][(wm + mt * 16 + l16) * 32 + quad * 8];
#pragma unroll
        for (int nt = 0; nt < 2; ++nt)
            bf[nt] = *(const bf16x8*)&Bs[b][(wn + nt * 16 + l16) * 32 + quad * 8];
#pragma unroll
        for (int mt = 0; mt < 4; ++mt)
#pragma unroll
            for (int nt = 0; nt < 2; ++nt)
                acc[mt][nt] = __builtin_amdgcn_mfma_f32_16x16x32_bf16(
                    af[mt], bf[nt], acc[mt][nt], 0, 0, 0);
    }
#pragma unroll
    for (int mt = 0; mt < 4; ++mt) {
#pragma unroll
        for (int nt = 0; nt < 2; ++nt) {
            int gcol = bn + wn + nt * 16 + l16;
            float b = bias[gcol];
#pragma unroll
            for (int r = 0; r < 4; ++r) {
                int grow = bm + wm + mt * 16 + quad * 4 + r;
                if (grow < THW_) {
                    float v = acc[mt][nt][r] + b;
                    if (gcol < QK_)
                        qkvb[(size_t)grow * QK_ + gcol] = f2bf(v);
                    else if (gcol < QKV_)
                        vb[(size_t)grow * DIM_ + (gcol - QK_)] = f2bf(v);
                    else
                        A2[(size_t)grow * KTOT_ + (gcol - QKV_ + DIM_)] = f2bf(siluf(v));
                }
            }
        }
    }
}

// ---------------------------------------------------------------------------
// K4: per (head, token) wave: LN(q), LN(k) over DH=48, RoPE, q*=1/sqrt(48)
// ---------------------------------------------------------------------------
__global__ __launch_bounds__(256) void qkln_rope_kernel(
    const unsigned short* __restrict__ qkv,
    const float* __restrict__ qn_w, const float* __restrict__ qn_b,
    const float* __restrict__ kn_w, const float* __restrict__ kn_b,
    unsigned short* __restrict__ qb, unsigned short* __restrict__ kb)
{
    int tid = threadIdx.x;
    int lane = tid & 63, wid = tid >> 6;
    int idx = blockIdx.x * 4 + wid;
    int head = idx / THW_;
    int m = idx - head * THW_;
    const unsigned short* fp = qkv + (size_t)m * QK_ + head * DH_;
    float qv = 0.f, kv = 0.f;
    if (lane < DH_) { qv = bf2f(fp[lane]); kv = bf2f(fp[768 + lane]); }
    float s = qv, sq = qv * qv, sk = kv, sqk = kv * kv;
#pragma unroll
    for (int off = 32; off > 0; off >>= 1) {
        s   += __shfl_xor(s, off, 64);
        sq  += __shfl_xor(sq, off, 64);
        sk  += __shfl_xor(sk, off, 64);
        sqk += __shfl_xor(sqk, off, 64);
    }
    float mq = s  * (1.f / 48.f), vq = sq  * (1.f / 48.f) - mq * mq;
    float mk = sk * (1.f / 48.f), vk = sqk * (1.f / 48.f) - mk * mk;
    float qn = 0.f, kn = 0.f;
    if (lane < DH_) {
        qn = (qv - mq) * rsqrtf(vq + EPS_) * qn_w[lane] + qn_b[lane];
        kn = (kv - mk) * rsqrtf(vk + EPS_) * kn_w[lane] + kn_b[lane];
    }
    int t = m / HW_; int hw = m - t * HW_;
    int hh = hw / RES_; int ww = hw - hh * RES_;
    int i = lane >> 1;
    int grp = i >> 3, j = i & 7;
    float pos = (grp == 0) ? (float)t : (grp == 1) ? (float)hh : (float)ww;
    float invf = exp2f(-1.6609640474436813f * (float)j);   // 10000^(-j/8)
    float ang = pos * invf;
    float cs = cosf(ang), sn = sinf(ang);
    float qp = __shfl_xor(qn, 1, 64);
    float kp = __shfl_xor(kn, 1, 64);
    float qo, ko;
    if ((lane & 1) == 0) { qo = qn * cs - qp * sn; ko = kn * cs - kp * sn; }
    else                 { qo = qp * sn + qn * cs; ko = kp * sn + kn * cs; }
    if (lane < DH_) {
        size_t o = ((size_t)head * THW_ + m) * DH_ + lane;
        qb[o] = f2bf(qo * 0.14433756729740643f);
        kb[o] = f2bf(ko);
    }
}

// ---------------------------------------------------------------------------
// K5: flash-style MFMA neighborhood attention (all-bf16 inputs).
// Ps overlaid on Ks -> 37.6 KB LDS, 4 blocks/CU.
// ---------------------------------------------------------------------------
__global__ __launch_bounds__(256) void attn_kernel(
    const unsigned short* __restrict__ qb, const unsigned short* __restrict__ kb,
    const unsigned short* __restrict__ vb, unsigned short* __restrict__ A2)
{
    __shared__ unsigned short U[64 * 168];    // Ks (144x72) / Ps (64x168) overlay
    __shared__ unsigned short Vt[48 * 168];   // [dim][key(pad 168, zero 144..)]

    int tid = threadIdx.x;
    int lane = tid & 63, wave = tid >> 6;
    int quad = lane >> 4, l16 = lane & 15;

    int head = blockIdx.x / 27;
    int tile = blockIdx.x - head * 27;
    int tt = tile / 9;
    int sp = tile - tt * 9;
    int h0 = (sp / 3) * 8;
    int w0 = (sp - (sp / 3) * 3) * 8;
    int u0h = min(max(h0 - 2, 0), RES_ - 12);
    int u0w = min(max(w0 - 2, 0), RES_ - 12);

    const unsigned short* qbh = qb + (size_t)head * THW_ * DH_;
    const unsigned short* kbh = kb + (size_t)head * THW_ * DH_;
    const unsigned short* vbh = vb + head * DH_;

    for (int i = tid; i < 48 * 24; i += 256) {
        int r = i / 24;
        Vt[r * 168 + 144 + (i - r * 24)] = 0;
    }

    int qbase = wave * 16;
    bf16x8 qf0, qf1;
    {
        int g = qbase + l16;
        int qtok = tt * HW_ + (h0 + (g >> 3)) * RES_ + (w0 + (g & 7));
        const unsigned short* qp = qbh + (size_t)qtok * DH_;
        qf0 = *(const bf16x8*)(qp + quad * 8);
        if (quad < 2) qf1 = *(const bf16x8*)(qp + 32 + quad * 8);
        else {
#pragma unroll
            for (int i = 0; i < 8; ++i) qf1[i] = 0;
        }
    }

    int vmask[4];
#pragma unroll
    for (int r = 0; r < 4; ++r) {
        int g = qbase + quad * 4 + r;
        int qh = h0 + (g >> 3), qw = w0 + (g & 7);
        int hs = min(max(qh - 2, 0), RES_ - 5);
        int ws = min(max(qw - 2, 0), RES_ - 5);
        int vm = 0;
#pragma unroll
        for (int nt = 0; nt < 9; ++nt) {
            int kk = nt * 16 + l16;
            int hc = u0h + kk / 12;
            int wc = u0w + kk - (kk / 12) * 12;
            int ok = (hc >= hs) & (hc < hs + 5) & (wc >= ws) & (wc < ws + 5);
            vm |= ok << nt;
        }
        vmask[r] = vm;
    }

    float mrow[4] = {-1e30f, -1e30f, -1e30f, -1e30f};
    float lrow[4] = {};
    f32x4 Oacc[3] = {};
    ushort4 z4; z4.x = 0; z4.y = 0; z4.z = 0; z4.w = 0;

    for (int a = 0; a < T_; ++a) {
        for (int i = tid; i < 144 * 12; i += 256) {
            int kk = i / 12;
            int g = i - kk * 12;
            int hc = u0h + kk / 12;
            int wc = u0w + kk - (kk / 12) * 12;
            int tok = a * HW_ + hc * RES_ + wc;
            ushort4 k4 = *(const ushort4*)(kbh + (size_t)tok * DH_ + 4 * g);
            *(ushort4*)&U[kk * 72 + 4 * g] = k4;
            ushort4 v4 = *(const ushort4*)(vbh + (size_t)tok * DIM_ + 4 * g);
            Vt[(4 * g + 0) * 168 + kk] = v4.x;
            Vt[(4 * g + 1) * 168 + kk] = v4.y;
            Vt[(4 * g + 2) * 168 + kk] = v4.z;
            Vt[(4 * g + 3) * 168 + kk] = v4.w;
        }
        for (int i = tid; i < 144 * 6; i += 256) {
            int kk = i / 6;
            int g = i - kk * 6;
            *(ushort4*)&U[kk * 72 + 48 + 4 * g] = z4;
        }
        __syncthreads();

        f32x4 sc[9];
#pragma unroll
        for (int nt = 0; nt < 9; ++nt) {
            bf16x8 kf0 = *(const bf16x8*)&U[(nt * 16 + l16) * 72 + quad * 8];
            bf16x8 kf1 = *(const bf16x8*)&U[(nt * 16 + l16) * 72 + 32 + quad * 8];
            f32x4 z = {};
            z = __builtin_amdgcn_mfma_f32_16x16x32_bf16(qf0, kf0, z, 0, 0, 0);
            sc[nt] = __builtin_amdgcn_mfma_f32_16x16x32_bf16(qf1, kf1, z, 0, 0, 0);
        }
        __syncthreads();   // all waves done reading Ks; U becomes Ps

        float rmax[4] = {-1e30f, -1e30f, -1e30f, -1e30f};
#pragma unroll
        for (int nt = 0; nt < 9; ++nt)
#pragma unroll
            for (int r = 0; r < 4; ++r) {
                float s = ((vmask[r] >> nt) & 1) ? sc[nt][r] : -1e30f;
                sc[nt][r] = s;
                rmax[r] = fmaxf(rmax[r], s);
            }
#pragma unroll
        for (int off = 1; off < 16; off <<= 1)
#pragma unroll
            for (int r = 0; r < 4; ++r)
                rmax[r] = fmaxf(rmax[r], __shfl_xor(rmax[r], off));
        float alpha[4], rsum[4] = {};
#pragma unroll
        for (int r = 0; r < 4; ++r) {
            float mn = fmaxf(mrow[r], rmax[r]);
            alpha[r] = expf(mrow[r] - mn);
            mrow[r] = mn;
        }
#pragma unroll
        for (int nt = 0; nt < 9; ++nt)
#pragma unroll
            for (int r = 0; r < 4; ++r) {
                float p = expf(sc[nt][r] - mrow[r]);
                rsum[r] += p;
                U[(qbase + quad * 4 + r) * 168 + nt * 16 + l16] = f2bf(p);
            }
        {
            int rr = lane >> 2, cc = (lane & 3) * 4;
            *(ushort4*)&U[(qbase + rr) * 168 + 144 + cc] = z4;
        }
#pragma unroll
        for (int off = 1; off < 16; off <<= 1)
#pragma unroll
            for (int r = 0; r < 4; ++r)
                rsum[r] += __shfl_xor(rsum[r], off);
#pragma unroll
        for (int r = 0; r < 4; ++r)
            lrow[r] = lrow[r] * alpha[r] + rsum[r];
#pragma unroll
        for (int vt = 0; vt < 3; ++vt)
#pragma unroll
            for (int r = 0; r < 4; ++r)
                Oacc[vt][r] *= alpha[r];

#pragma unroll
        for (int ks = 0; ks < 5; ++ks) {
            bf16x8 pf = *(const bf16x8*)&U[(qbase + l16) * 168 + ks * 32 + quad * 8];
#pragma unroll
            for (int vt = 0; vt < 3; ++vt) {
                bf16x8 vf = *(const bf16x8*)&Vt[(vt * 16 + l16) * 168 + ks * 32 + quad * 8];
                Oacc[vt] = __builtin_amdgcn_mfma_f32_16x16x32_bf16(pf, vf, Oacc[vt], 0, 0, 0);
            }
        }
        __syncthreads();
    }

#pragma unroll
    for (int r = 0; r < 4; ++r) {
        int g = qbase + quad * 4 + r;
        int m = tt * HW_ + (h0 + (g >> 3)) * RES_ + (w0 + (g & 7));
        float inv = 1.f / lrow[r];
#pragma unroll
        for (int vt = 0; vt < 3; ++vt) {
            int d = vt * 16 + l16;
            A2[(size_t)m * KTOT_ + head * DH_ + d] = f2bf(Oacc[vt][r] * inv);
        }
    }
}

// ---------------------------------------------------------------------------
// K6: MFMA GEMM2 (split-K=6) + fused reduction tail (last-block-done):
// P[s] = A2(1792x3840) @ Bt2^T(768x3840); 6th arriver per (m,n) tile sums
// slices + x + b_mlp and writes out in (t,c,hw) layout.
// LDS: manual union so reduce tile reuses the staging buffers (24 KB total).
// ---------------------------------------------------------------------------
__global__ __launch_bounds__(256) void gemm2_kernel(
    const unsigned short* __restrict__ A,   // 1792 x 3840
    const unsigned short* __restrict__ Bt,  // 768 x 3840
    unsigned short* __restrict__ P,         // 6 x 1792 x 768
    const float* __restrict__ x, const float* __restrict__ b_mlp,
    float* __restrict__ out, int* __restrict__ cnt)
{
    const int K = KTOT_;
    const int NI = (KTOT_ / SPLITK_) / 32;  // 20
    __shared__ __align__(16) unsigned short smem[12288];  // 24576 B
    unsigned short* As0 = smem;             // [2][128*32]
    unsigned short* Bs0 = smem + 8192;      // [2][64*32]
    __shared__ int done_flag;
    int tid = threadIdx.x;
    int bm = blockIdx.y * 128;
    int bn = blockIdx.x * 64;
    int ks = blockIdx.z * (KTOT_ / SPLITK_);
    int wave = tid >> 6, lane = tid & 63;
    int quad = lane >> 4, l16 = lane & 15;
    int wm = (wave & 1) * 64;
    int wn = (wave >> 1) * 32;
    f32x4 acc[4][2] = {};
    int arow0 = tid >> 2,         akoff0 = (tid & 3) * 8;
    int arow1 = (tid + 256) >> 2, akoff1 = (tid & 3) * 8;
    int brow = tid >> 2,          bkoff = (tid & 3) * 8;
    const unsigned short* Ag0 = A + (size_t)(bm + arow0) * K + akoff0 + ks;
    const unsigned short* Ag1 = A + (size_t)(bm + arow1) * K + akoff1 + ks;
    const unsigned short* Bg  = Bt + (size_t)(bn + brow) * K + bkoff + ks;
    int la0 = arow0 * 32 + akoff0;
    int la1 = arow1 * 32 + akoff1;
    int lb  = brow * 32 + bkoff;
    async_copy16(Ag0, &As0[la0]);
    async_copy16(Ag1, &As0[la1]);
    async_copy16(Bg,  &Bs0[lb]);
    for (int i = 0; i < NI; ++i) {
        __syncthreads();
        if (i + 1 < NI) {
            int k0 = (i + 1) * 32;
            int b = (i + 1) & 1;
            async_copy16(Ag0 + k0, &As0[b * 4096 + la0]);
            async_copy16(Ag1 + k0, &As0[b * 4096 + la1]);
            async_copy16(Bg + k0,  &Bs0[b * 2048 + lb]);
        }
        int b = i & 1;
        bf16x8 af[4], bf[2];
#pragma unroll
        for (int mt = 0; mt < 4; ++mt)
            af[mt] = *(const bf16x8*)&As0[b * 4096 + (wm + mt * 16 + l16) * 32 + quad * 8];
#pragma unroll
        for (int nt = 0; nt < 2; ++nt)
            bf[nt] = *(const bf16x8*)&Bs0[b * 2048 + (wn + nt * 16 + l16) * 32 + quad * 8];
#pragma unroll
        for (int mt = 0; mt < 4; ++mt)
#pragma unroll
            for (int nt = 0; nt < 2; ++nt)
                acc[mt][nt] = __builtin_amdgcn_mfma_f32_16x16x32_bf16(
                    af[mt], bf[nt], acc[mt][nt], 0, 0, 0);
    }
    unsigned short* Pp = P + (size_t)blockIdx.z * MP_ * DIM_;
#pragma unroll
    for (int mt = 0; mt < 4; ++mt) {
#pragma unroll
        for (int nt = 0; nt < 2; ++nt) {
            int gcol = bn + wn + nt * 16 + l16;
#pragma unroll
            for (int r = 0; r < 4; ++r) {
                int grow = bm + wm + mt * 16 + quad * 4 + r;
                if (grow < THW_)
                    Pp[(size_t)grow * DIM_ + gcol] = f2bf(acc[mt][nt][r]);
            }
        }
    }
    // --- last-block-done reduction (canonical threadfence pattern) ---
    __threadfence();
    __syncthreads();
    if (tid == 0)
        done_flag = atomicAdd(&cnt[blockIdx.y * 12 + blockIdx.x], 1);
    __syncthreads();
    if (done_flag != SPLITK_ - 1) return;
    __threadfence();                         // acquire: see all slices
    float (*rt)[65] = (float(*)[65])smem;    // 32 x 65 fp32 = 8.3 KB
    for (int sub = 0; sub < 4; ++sub) {
        int m0 = bm + (sub >> 1) * 64;
        int n0 = bn + (sub & 1) * 32;
        if (m0 >= THW_) break;
        int t = m0 / HW_;
        int hw0 = m0 - t * HW_;
        for (int i = tid; i < 512; i += 256) {
            int ml = i >> 3;
            int n4 = (i & 7) * 4;
            float s0 = 0.f, s1 = 0.f, s2 = 0.f, s3 = 0.f;
#pragma unroll
            for (int sI = 0; sI < SPLITK_; ++sI) {
                const unsigned short* pp =
                    P + ((size_t)sI * MP_ + m0 + ml) * DIM_ + n0 + n4;
                ushort4 u = *(const ushort4*)pp;
                s0 += bf2f(u.x); s1 += bf2f(u.y);
                s2 += bf2f(u.z); s3 += bf2f(u.w);
            }
            rt[n4 + 0][ml] = s0;
            rt[n4 + 1][ml] = s1;
            rt[n4 + 2][ml] = s2;
            rt[n4 + 3][ml] = s3;
        }
        __syncthreads();
        for (int i = tid; i < 512; i += 256) {
            int n = i >> 4;
            int ms = (i & 15) * 4;
            int gn = n0 + n;
            size_t base = ((size_t)t * DIM_ + gn) * HW_ + hw0 + ms;
            float bv = b_mlp[gn];
            float4 xv = *(const float4*)(x + base);
            float4 o;
            o.x = xv.x + bv + rt[n][ms + 0];
            o.y = xv.y + bv + rt[n][ms + 1];
            o.z = xv.z + bv + rt[n][ms + 2];
            o.w = xv.w + bv + rt[n][ms + 3];
            *(float4*)(out + base) = o;
        }
        __syncthreads();
    }
}

// ---------------------------------------------------------------------------
extern "C" void kernel_launch(void* const* d_in, const int* in_sizes, int n_in,
                              void* d_out, int out_size, void* d_ws, size_t ws_size,
                              hipStream_t stream) {
    const float* x       = (const float*)d_in[0];
    const float* emb     = (const float*)d_in[1];
    const float* w_mod   = (const float*)d_in[2];
    const float* b_mod   = (const float*)d_in[3];
    const float* qn_w    = (const float*)d_in[4];
    const float* qn_b    = (const float*)d_in[5];
    const float* kn_w    = (const float*)d_in[6];
    const float* kn_b    = (const float*)d_in[7];
    const float* W_fused = (const float*)d_in[8];
    const float* b_fused = (const float*)d_in[9];
    const float* W_out   = (const float*)d_in[10];
    const float* W_mlp   = (const float*)d_in[11];
    const float* b_mlp   = (const float*)d_in[12];
    float* out = (float*)d_out;

    char* w = (char*)d_ws;
    float* mod = (float*)w;            w += (size_t)4608 * 4;
    unsigned short* qkv = (unsigned short*)w;  w += (size_t)THW_ * QK_ * 2;
    unsigned short* vb  = (unsigned short*)w;  w += (size_t)THW_ * DIM_ * 2;
    unsigned short* qb  = (unsigned short*)w;  w += (size_t)HEADS_ * THW_ * DH_ * 2;
    unsigned short* kb  = (unsigned short*)w;  w += (size_t)HEADS_ * THW_ * DH_ * 2;
    unsigned short* h   = (unsigned short*)w;  w += (size_t)MP_ * DIM_ * 2;
    unsigned short* A2  = (unsigned short*)w;  w += (size_t)MP_ * KTOT_ * 2;
    unsigned short* Bt1 = (unsigned short*)w;  w += (size_t)NF_ * DIM_ * 2;
    unsigned short* Bt2 = (unsigned short*)w;  w += (size_t)DIM_ * KTOT_ * 2;
    unsigned short* P   = (unsigned short*)w;  w += (size_t)SPLITK_ * MP_ * DIM_ * 2;
    int* cnt            = (int*)w;             w += (size_t)NCNT_ * 4;

    mod_kernel<<<dim3(12, 3), 256, 0, stream>>>(emb, w_mod, b_mod, mod, cnt);
    prep_ln_kernel<<<7344, 256, 0, stream>>>(W_fused, Bt1, W_out, W_mlp, Bt2,
                                             x, mod, h);
    gemm1_kernel<<<dim3(NF_ / 64, MP_ / 128), 256, 0, stream>>>(h, Bt1, b_fused, qkv, vb, A2);
    qkln_rope_kernel<<<(HEADS_ * THW_) / 4, 256, 0, stream>>>(qkv, qn_w, qn_b, kn_w, kn_b, qb, kb);
    attn_kernel<<<HEADS_ * 27, 256, 0, stream>>>(qb, kb, vb, A2);
    gemm2_kernel<<<dim3(DIM_ / 64, MP_ / 128, SPLITK_), 256, 0, stream>>>(
        A2, Bt2, P, x, b_mlp, out, cnt);
}

// Round 12
// 231.491 us; speedup vs baseline: 1.6595x; 1.6595x over previous
//
#include <hip/hip_runtime.h>
#include <hip/hip_bf16.h>
#include <math.h>

#define T_    3
#define RES_  24
#define DIM_  768
#define HEADS_ 16
#define DH_   48
#define EMB_  1024
#define HW_   576            // RES*RES
#define THW_  1728           // T*HW
#define MP_   1792           // THW padded to multiple of 128
#define MLP_  3072
#define NF_   5376           // 3*DIM + MLP
#define QKV_  2304           // 3*DIM
#define QK_   1536           // 2*DIM (q,k only)
#define KTOT_ 3840           // DIM + MLP (second GEMM K)
#define SPLITK_ 6
#define EPS_  1e-5f

typedef __attribute__((ext_vector_type(8))) short bf16x8;
typedef __attribute__((ext_vector_type(4))) float f32x4;

__device__ __forceinline__ float siluf(float x) { return x / (1.f + expf(-x)); }

__device__ __forceinline__ unsigned short f2bf(float f) {
    __hip_bfloat16 b = __float2bfloat16(f);
    return *reinterpret_cast<unsigned short*>(&b);
}

__device__ __forceinline__ float bf2f(unsigned short u) {
    return __uint_as_float(((unsigned)u) << 16);
}

__device__ __forceinline__ void async_copy16(const void* g, void* l) {
    __builtin_amdgcn_global_load_lds(
        (__attribute__((address_space(1))) void*)g,
        (__attribute__((address_space(3))) void*)l,
        16, 0, 0);
}

// ---------------------------------------------------------------------------
// K0: fused prep — three independent sub-jobs, block-range partitioned:
//   b in [0,4032):    W_fused (768x5376 f32) -> Bt1 (5376x768 bf16) transposed
//   b in [4032,6912): [W_out;W_mlp] (3840x768) -> Bt2 (768x3840 bf16) transp.
//   b in [6912,6948): mod[t] = silu(emb[t]) @ w_mod + b_mod  (3x1536)
// ---------------------------------------------------------------------------
__global__ __launch_bounds__(256) void prep_kernel(
    const float* __restrict__ W_fused, unsigned short* __restrict__ Bt1,
    const float* __restrict__ W_out, const float* __restrict__ W_mlp,
    unsigned short* __restrict__ Bt2,
    const float* __restrict__ emb, const float* __restrict__ w_mod,
    const float* __restrict__ b_mod, float* __restrict__ mod)
{
    __shared__ float buf[1152];
    int b = blockIdx.x;
    int tid = threadIdx.x;
    if (b < 4032) {
        float (*tile)[33] = (float(*)[33])buf;
        int n0 = (b % 168) * 32;
        int k0 = (b / 168) * 32;
        int c = tid & 31, r = tid >> 5;
#pragma unroll
        for (int i = 0; i < 4; ++i)
            tile[r + 8 * i][c] = W_fused[(size_t)(k0 + r + 8 * i) * NF_ + n0 + c];
        __syncthreads();
#pragma unroll
        for (int i = 0; i < 4; ++i)
            Bt1[(size_t)(n0 + r + 8 * i) * DIM_ + k0 + c] = f2bf(tile[c][r + 8 * i]);
    } else if (b < 6912) {
        int b2 = b - 4032;
        float (*tile)[33] = (float(*)[33])buf;
        int k0 = (b2 % 120) * 32;
        int n0 = (b2 / 120) * 32;
        int c = tid & 31, r = tid >> 5;
#pragma unroll
        for (int i = 0; i < 4; ++i) {
            int k = k0 + r + 8 * i;
            float v = (k < DIM_) ? W_out[(size_t)k * DIM_ + n0 + c]
                                 : W_mlp[(size_t)(k - DIM_) * DIM_ + n0 + c];
            tile[r + 8 * i][c] = v;
        }
        __syncthreads();
#pragma unroll
        for (int i = 0; i < 4; ++i)
            Bt2[(size_t)(n0 + r + 8 * i) * KTOT_ + k0 + c] = f2bf(tile[c][r + 8 * i]);
    } else {
        int b3 = b - 6912;
        int t = b3 / 12;
        int chunk = b3 - t * 12;
        float* se = buf;             // 1024
        float* part = buf + 1024;    // 128
        for (int i = tid; i < EMB_; i += 256) {
            float e = emb[t * EMB_ + i];
            se[i] = e / (1.f + expf(-e));
        }
        __syncthreads();
        int r = tid >> 7;
        int c = tid & 127;
        int j = chunk * 128 + c;
        const float* wp = w_mod + j;
        float acc = 0.f;
        for (int e = r * 512; e < r * 512 + 512; ++e)
            acc += se[e] * wp[e * 1536];
        if (r == 1) part[c] = acc;
        __syncthreads();
        if (r == 0)
            mod[t * 1536 + j] = acc + part[c] + b_mod[j];
    }
}

// ---------------------------------------------------------------------------
// K2: LN+modulate, 4 tokens per block (float4 loads along hw)
// ---------------------------------------------------------------------------
__global__ __launch_bounds__(256) void ln_mod_kernel(
    const float* __restrict__ x, const float* __restrict__ mod,
    unsigned short* __restrict__ h)
{
    int m0 = blockIdx.x * 4;
    int t = m0 / HW_;
    int hw0 = m0 - t * HW_;
    const float* xp = x + (size_t)t * DIM_ * HW_ + hw0;
    int tid = threadIdx.x;
    float4 X0 = *(const float4*)(xp + (size_t)tid * HW_);
    float4 X1 = *(const float4*)(xp + (size_t)(tid + 256) * HW_);
    float4 X2 = *(const float4*)(xp + (size_t)(tid + 512) * HW_);
    float4 sv, sqv;
    sv.x = X0.x + X1.x + X2.x;  sv.y = X0.y + X1.y + X2.y;
    sv.z = X0.z + X1.z + X2.z;  sv.w = X0.w + X1.w + X2.w;
    sqv.x = X0.x*X0.x + X1.x*X1.x + X2.x*X2.x;
    sqv.y = X0.y*X0.y + X1.y*X1.y + X2.y*X2.y;
    sqv.z = X0.z*X0.z + X1.z*X1.z + X2.z*X2.z;
    sqv.w = X0.w*X0.w + X1.w*X1.w + X2.w*X2.w;
#pragma unroll
    for (int off = 32; off > 0; off >>= 1) {
        sv.x += __shfl_xor(sv.x, off, 64);  sv.y += __shfl_xor(sv.y, off, 64);
        sv.z += __shfl_xor(sv.z, off, 64);  sv.w += __shfl_xor(sv.w, off, 64);
        sqv.x += __shfl_xor(sqv.x, off, 64); sqv.y += __shfl_xor(sqv.y, off, 64);
        sqv.z += __shfl_xor(sqv.z, off, 64); sqv.w += __shfl_xor(sqv.w, off, 64);
    }
    __shared__ float4 ssum[4], ssq[4];
    int lane = tid & 63, wid = tid >> 6;
    if (lane == 0) { ssum[wid] = sv; ssq[wid] = sqv; }
    __syncthreads();
    float mean[4], rs[4];
#pragma unroll
    for (int j = 0; j < 4; ++j) {
        float tot  = ((const float*)&ssum[0])[j] + ((const float*)&ssum[1])[j]
                   + ((const float*)&ssum[2])[j] + ((const float*)&ssum[3])[j];
        float totq = ((const float*)&ssq[0])[j] + ((const float*)&ssq[1])[j]
                   + ((const float*)&ssq[2])[j] + ((const float*)&ssq[3])[j];
        float mn = tot * (1.f / 768.f);
        float var = totq * (1.f / 768.f) - mn * mn;
        mean[j] = mn;
        rs[j] = rsqrtf(var + EPS_);
    }
    const float* sc = mod + t * 1536;
    const float* sh = sc + 768;
#pragma unroll
    for (int cc = 0; cc < 3; ++cc) {
        int c = tid + cc * 256;
        float4 X = (cc == 0) ? X0 : (cc == 1) ? X1 : X2;
        float scl = 1.f + sc[c];
        float shf = sh[c];
        const float* Xp = (const float*)&X;
#pragma unroll
        for (int j = 0; j < 4; ++j)
            h[(size_t)(m0 + j) * DIM_ + c] =
                f2bf((Xp[j] - mean[j]) * rs[j] * scl + shf);
    }
}

// ---------------------------------------------------------------------------
// K3: MFMA GEMM1, 128x64 tile, double-buffered LDS, 1 barrier/iter.
// C = h(1792x768) @ Bt1^T(5376x768) + b_fused
// ---------------------------------------------------------------------------
__global__ __launch_bounds__(256) void gemm1_kernel(
    const unsigned short* __restrict__ A,   // 1792 x 768
    const unsigned short* __restrict__ Bt,  // 5376 x 768
    const float* __restrict__ bias,
    unsigned short* __restrict__ qkvb,      // 1728 x 1536 (q,k bf16)
    unsigned short* __restrict__ vb,        // 1728 x 768 (v, bf16)
    unsigned short* __restrict__ A2)        // 1792 x 3840
{
    const int K = DIM_;
    const int NI = K / 32;                  // 24
    __shared__ unsigned short As[2][128 * 32];
    __shared__ unsigned short Bs[2][64 * 32];
    int tid = threadIdx.x;
    int bm = blockIdx.y * 128;
    int bn = blockIdx.x * 64;
    int wave = tid >> 6, lane = tid & 63;
    int quad = lane >> 4, l16 = lane & 15;
    int wm = (wave & 1) * 64;
    int wn = (wave >> 1) * 32;
    f32x4 acc[4][2] = {};
    int arow0 = tid >> 2,             akoff0 = (tid & 3) * 8;
    int arow1 = (tid + 256) >> 2,     akoff1 = (tid & 3) * 8;
    int brow = tid >> 2,              bkoff = (tid & 3) * 8;
    const unsigned short* Ag0 = A + (size_t)(bm + arow0) * K + akoff0;
    const unsigned short* Ag1 = A + (size_t)(bm + arow1) * K + akoff1;
    const unsigned short* Bg  = Bt + (size_t)(bn + brow) * K + bkoff;
    int la0 = arow0 * 32 + akoff0;
    int la1 = arow1 * 32 + akoff1;
    int lb  = brow * 32 + bkoff;
    async_copy16(Ag0, &As[0][la0]);
    async_copy16(Ag1, &As[0][la1]);
    async_copy16(Bg,  &Bs[0][lb]);
    for (int i = 0; i < NI; ++i) {
        __syncthreads();
        if (i + 1 < NI) {
            int k0 = (i + 1) * 32;
            int b = (i + 1) & 1;
            async_copy16(Ag0 + k0, &As[b][la0]);
            async_copy16(Ag1 + k0, &As[b][la1]);
            async_copy16(Bg + k0,  &Bs[b][lb]);
        }
        int b = i & 1;
        bf16x8 af[4], bf[2];
#pragma unroll
        for (int mt = 0; mt < 4; ++mt)
            af[mt] = *(const bf16x8*)&As[b][(wm + mt * 16 + l16) * 32 + quad * 8];
#pragma unroll
        for (int nt = 0; nt < 2; ++nt)
            bf[nt] = *(const bf16x8*)&Bs[b][(wn + nt * 16 + l16) * 32 + quad * 8];
#pragma unroll
        for (int mt = 0; mt < 4; ++mt)
#pragma unroll
            for (int nt = 0; nt < 2; ++nt)
                acc[mt][nt] = __builtin_amdgcn_mfma_f32_16x16x32_bf16(
                    af[mt], bf[nt], acc[mt][nt], 0, 0, 0);
    }
#pragma unroll
    for (int mt = 0; mt < 4; ++mt) {
#pragma unroll
        for (int nt = 0; nt < 2; ++nt) {
            int gcol = bn + wn + nt * 16 + l16;
            float b = bias[gcol];
#pragma unroll
            for (int r = 0; r < 4; ++r) {
                int grow = bm + wm + mt * 16 + quad * 4 + r;
                if (grow < THW_) {
                    float v = acc[mt][nt][r] + b;
                    if (gcol < QK_)
                        qkvb[(size_t)grow * QK_ + gcol] = f2bf(v);
                    else if (gcol < QKV_)
                        vb[(size_t)grow * DIM_ + (gcol - QK_)] = f2bf(v);
                    else
                        A2[(size_t)grow * KTOT_ + (gcol - QKV_ + DIM_)] = f2bf(siluf(v));
                }
            }
        }
    }
}

// ---------------------------------------------------------------------------
// K4: per (head, token) wave: LN(q), LN(k) over DH=48, RoPE, q*=1/sqrt(48)
// ---------------------------------------------------------------------------
__global__ __launch_bounds__(256) void qkln_rope_kernel(
    const unsigned short* __restrict__ qkv,
    const float* __restrict__ qn_w, const float* __restrict__ qn_b,
    const float* __restrict__ kn_w, const float* __restrict__ kn_b,
    unsigned short* __restrict__ qb, unsigned short* __restrict__ kb)
{
    int tid = threadIdx.x;
    int lane = tid & 63, wid = tid >> 6;
    int idx = blockIdx.x * 4 + wid;
    int head = idx / THW_;
    int m = idx - head * THW_;
    const unsigned short* fp = qkv + (size_t)m * QK_ + head * DH_;
    float qv = 0.f, kv = 0.f;
    if (lane < DH_) { qv = bf2f(fp[lane]); kv = bf2f(fp[768 + lane]); }
    float s = qv, sq = qv * qv, sk = kv, sqk = kv * kv;
#pragma unroll
    for (int off = 32; off > 0; off >>= 1) {
        s   += __shfl_xor(s, off, 64);
        sq  += __shfl_xor(sq, off, 64);
        sk  += __shfl_xor(sk, off, 64);
        sqk += __shfl_xor(sqk, off, 64);
    }
    float mq = s  * (1.f / 48.f), vq = sq  * (1.f / 48.f) - mq * mq;
    float mk = sk * (1.f / 48.f), vk = sqk * (1.f / 48.f) - mk * mk;
    float qn = 0.f, kn = 0.f;
    if (lane < DH_) {
        qn = (qv - mq) * rsqrtf(vq + EPS_) * qn_w[lane] + qn_b[lane];
        kn = (kv - mk) * rsqrtf(vk + EPS_) * kn_w[lane] + kn_b[lane];
    }
    int t = m / HW_; int hw = m - t * HW_;
    int hh = hw / RES_; int ww = hw - hh * RES_;
    int i = lane >> 1;
    int grp = i >> 3, j = i & 7;
    float pos = (grp == 0) ? (float)t : (grp == 1) ? (float)hh : (float)ww;
    float invf = exp2f(-1.6609640474436813f * (float)j);   // 10000^(-j/8)
    float ang = pos * invf;
    float cs = cosf(ang), sn = sinf(ang);
    float qp = __shfl_xor(qn, 1, 64);
    float kp = __shfl_xor(kn, 1, 64);
    float qo, ko;
    if ((lane & 1) == 0) { qo = qn * cs - qp * sn; ko = kn * cs - kp * sn; }
    else                 { qo = qp * sn + qn * cs; ko = kp * sn + kn * cs; }
    if (lane < DH_) {
        size_t o = ((size_t)head * THW_ + m) * DH_ + lane;
        qb[o] = f2bf(qo * 0.14433756729740643f);
        kb[o] = f2bf(ko);
    }
}

// ---------------------------------------------------------------------------
// K5: flash-style MFMA neighborhood attention (all-bf16 inputs).
// Ps overlaid on Ks -> 37.6 KB LDS, 4 blocks/CU.
// HARDENING vs R9: explicit __syncthreads() between Ps writes and the P.V
// MFMA reads — removes reliance on cross-lane same-wave LDS write->read
// ordering (suspected flaky race in R11's post-timing divergence).
// ---------------------------------------------------------------------------
__global__ __launch_bounds__(256) void attn_kernel(
    const unsigned short* __restrict__ qb, const unsigned short* __restrict__ kb,
    const unsigned short* __restrict__ vb, unsigned short* __restrict__ A2)
{
    __shared__ unsigned short U[64 * 168];    // Ks (144x72) / Ps (64x168) overlay
    __shared__ unsigned short Vt[48 * 168];   // [dim][key(pad 168, zero 144..)]

    int tid = threadIdx.x;
    int lane = tid & 63, wave = tid >> 6;
    int quad = lane >> 4, l16 = lane & 15;

    int head = blockIdx.x / 27;
    int tile = blockIdx.x - head * 27;
    int tt = tile / 9;
    int sp = tile - tt * 9;
    int h0 = (sp / 3) * 8;
    int w0 = (sp - (sp / 3) * 3) * 8;
    int u0h = min(max(h0 - 2, 0), RES_ - 12);
    int u0w = min(max(w0 - 2, 0), RES_ - 12);

    const unsigned short* qbh = qb + (size_t)head * THW_ * DH_;
    const unsigned short* kbh = kb + (size_t)head * THW_ * DH_;
    const unsigned short* vbh = vb + head * DH_;

    for (int i = tid; i < 48 * 24; i += 256) {
        int r = i / 24;
        Vt[r * 168 + 144 + (i - r * 24)] = 0;
    }

    int qbase = wave * 16;
    bf16x8 qf0, qf1;
    {
        int g = qbase + l16;
        int qtok = tt * HW_ + (h0 + (g >> 3)) * RES_ + (w0 + (g & 7));
        const unsigned short* qp = qbh + (size_t)qtok * DH_;
        qf0 = *(const bf16x8*)(qp + quad * 8);
        if (quad < 2) qf1 = *(const bf16x8*)(qp + 32 + quad * 8);
        else {
#pragma unroll
            for (int i = 0; i < 8; ++i) qf1[i] = 0;
        }
    }

    int vmask[4];
#pragma unroll
    for (int r = 0; r < 4; ++r) {
        int g = qbase + quad * 4 + r;
        int qh = h0 + (g >> 3), qw = w0 + (g & 7);
        int hs = min(max(qh - 2, 0), RES_ - 5);
        int ws = min(max(qw - 2, 0), RES_ - 5);
        int vm = 0;
#pragma unroll
        for (int nt = 0; nt < 9; ++nt) {
            int kk = nt * 16 + l16;
            int hc = u0h + kk / 12;
            int wc = u0w + kk - (kk / 12) * 12;
            int ok = (hc >= hs) & (hc < hs + 5) & (wc >= ws) & (wc < ws + 5);
            vm |= ok << nt;
        }
        vmask[r] = vm;
    }

    float mrow[4] = {-1e30f, -1e30f, -1e30f, -1e30f};
    float lrow[4] = {};
    f32x4 Oacc[3] = {};
    ushort4 z4; z4.x = 0; z4.y = 0; z4.z = 0; z4.w = 0;

    for (int a = 0; a < T_; ++a) {
        for (int i = tid; i < 144 * 12; i += 256) {
            int kk = i / 12;
            int g = i - kk * 12;
            int hc = u0h + kk / 12;
            int wc = u0w + kk - (kk / 12) * 12;
            int tok = a * HW_ + hc * RES_ + wc;
            ushort4 k4 = *(const ushort4*)(kbh + (size_t)tok * DH_ + 4 * g);
            *(ushort4*)&U[kk * 72 + 4 * g] = k4;
            ushort4 v4 = *(const ushort4*)(vbh + (size_t)tok * DIM_ + 4 * g);
            Vt[(4 * g + 0) * 168 + kk] = v4.x;
            Vt[(4 * g + 1) * 168 + kk] = v4.y;
            Vt[(4 * g + 2) * 168 + kk] = v4.z;
            Vt[(4 * g + 3) * 168 + kk] = v4.w;
        }
        for (int i = tid; i < 144 * 6; i += 256) {
            int kk = i / 6;
            int g = i - kk * 6;
            *(ushort4*)&U[kk * 72 + 48 + 4 * g] = z4;
        }
        __syncthreads();

        f32x4 sc[9];
#pragma unroll
        for (int nt = 0; nt < 9; ++nt) {
            bf16x8 kf0 = *(const bf16x8*)&U[(nt * 16 + l16) * 72 + quad * 8];
            bf16x8 kf1 = *(const bf16x8*)&U[(nt * 16 + l16) * 72 + 32 + quad * 8];
            f32x4 z = {};
            z = __builtin_amdgcn_mfma_f32_16x16x32_bf16(qf0, kf0, z, 0, 0, 0);
            sc[nt] = __builtin_amdgcn_mfma_f32_16x16x32_bf16(qf1, kf1, z, 0, 0, 0);
        }
        __syncthreads();   // all waves done reading Ks; U becomes Ps

        float rmax[4] = {-1e30f, -1e30f, -1e30f, -1e30f};
#pragma unroll
        for (int nt = 0; nt < 9; ++nt)
#pragma unroll
            for (int r = 0; r < 4; ++r) {
                float s = ((vmask[r] >> nt) & 1) ? sc[nt][r] : -1e30f;
                sc[nt][r] = s;
                rmax[r] = fmaxf(rmax[r], s);
            }
#pragma unroll
        for (int off = 1; off < 16; off <<= 1)
#pragma unroll
            for (int r = 0; r < 4; ++r)
                rmax[r] = fmaxf(rmax[r], __shfl_xor(rmax[r], off));
        float alpha[4], rsum[4] = {};
#pragma unroll
        for (int r = 0; r < 4; ++r) {
            float mn = fmaxf(mrow[r], rmax[r]);
            alpha[r] = expf(mrow[r] - mn);
            mrow[r] = mn;
        }
#pragma unroll
        for (int nt = 0; nt < 9; ++nt)
#pragma unroll
            for (int r = 0; r < 4; ++r) {
                float p = expf(sc[nt][r] - mrow[r]);
                rsum[r] += p;
                U[(qbase + quad * 4 + r) * 168 + nt * 16 + l16] = f2bf(p);
            }
        {
            int rr = lane >> 2, cc = (lane & 3) * 4;
            *(ushort4*)&U[(qbase + rr) * 168 + 144 + cc] = z4;
        }
        __syncthreads();   // publish Ps before MFMA reads (LDS-ordering hardening)
#pragma unroll
        for (int off = 1; off < 16; off <<= 1)
#pragma unroll
            for (int r = 0; r < 4; ++r)
                rsum[r] += __shfl_xor(rsum[r], off);
#pragma unroll
        for (int r = 0; r < 4; ++r)
            lrow[r] = lrow[r] * alpha[r] + rsum[r];
#pragma unroll
        for (int vt = 0; vt < 3; ++vt)
#pragma unroll
            for (int r = 0; r < 4; ++r)
                Oacc[vt][r] *= alpha[r];

#pragma unroll
        for (int ks = 0; ks < 5; ++ks) {
            bf16x8 pf = *(const bf16x8*)&U[(qbase + l16) * 168 + ks * 32 + quad * 8];
#pragma unroll
            for (int vt = 0; vt < 3; ++vt) {
                bf16x8 vf = *(const bf16x8*)&Vt[(vt * 16 + l16) * 168 + ks * 32 + quad * 8];
                Oacc[vt] = __builtin_amdgcn_mfma_f32_16x16x32_bf16(pf, vf, Oacc[vt], 0, 0, 0);
            }
        }
        __syncthreads();
    }

#pragma unroll
    for (int r = 0; r < 4; ++r) {
        int g = qbase + quad * 4 + r;
        int m = tt * HW_ + (h0 + (g >> 3)) * RES_ + (w0 + (g & 7));
        float inv = 1.f / lrow[r];
#pragma unroll
        for (int vt = 0; vt < 3; ++vt) {
            int d = vt * 16 + l16;
            A2[(size_t)m * KTOT_ + head * DH_ + d] = f2bf(Oacc[vt][r] * inv);
        }
    }
}

// ---------------------------------------------------------------------------
// K6: MFMA GEMM2 (split-K=6), 128x64 tile, double-buffered LDS:
// P[s] = A2(1792x3840) @ Bt2^T(768x3840), slice s
// ---------------------------------------------------------------------------
__global__ __launch_bounds__(256) void gemm2_kernel(
    const unsigned short* __restrict__ A,   // 1792 x 3840
    const unsigned short* __restrict__ Bt,  // 768 x 3840
    unsigned short* __restrict__ P)         // 6 x 1792 x 768
{
    const int K = KTOT_;
    const int NI = (KTOT_ / SPLITK_) / 32;  // 20
    __shared__ unsigned short As[2][128 * 32];
    __shared__ unsigned short Bs[2][64 * 32];
    int tid = threadIdx.x;
    int bm = blockIdx.y * 128;
    int bn = blockIdx.x * 64;
    int ks = blockIdx.z * (KTOT_ / SPLITK_);
    int wave = tid >> 6, lane = tid & 63;
    int quad = lane >> 4, l16 = lane & 15;
    int wm = (wave & 1) * 64;
    int wn = (wave >> 1) * 32;
    f32x4 acc[4][2] = {};
    int arow0 = tid >> 2,         akoff0 = (tid & 3) * 8;
    int arow1 = (tid + 256) >> 2, akoff1 = (tid & 3) * 8;
    int brow = tid >> 2,          bkoff = (tid & 3) * 8;
    const unsigned short* Ag0 = A + (size_t)(bm + arow0) * K + akoff0 + ks;
    const unsigned short* Ag1 = A + (size_t)(bm + arow1) * K + akoff1 + ks;
    const unsigned short* Bg  = Bt + (size_t)(bn + brow) * K + bkoff + ks;
    int la0 = arow0 * 32 + akoff0;
    int la1 = arow1 * 32 + akoff1;
    int lb  = brow * 32 + bkoff;
    async_copy16(Ag0, &As[0][la0]);
    async_copy16(Ag1, &As[0][la1]);
    async_copy16(Bg,  &Bs[0][lb]);
    for (int i = 0; i < NI; ++i) {
        __syncthreads();
        if (i + 1 < NI) {
            int k0 = (i + 1) * 32;
            int b = (i + 1) & 1;
            async_copy16(Ag0 + k0, &As[b][la0]);
            async_copy16(Ag1 + k0, &As[b][la1]);
            async_copy16(Bg + k0,  &Bs[b][lb]);
        }
        int b = i & 1;
        bf16x8 af[4], bf[2];
#pragma unroll
        for (int mt = 0; mt < 4; ++mt)
            af[mt] = *(const bf16x8*)&As[b][(wm + mt * 16 + l16) * 32 + quad * 8];
#pragma unroll
        for (int nt = 0; nt < 2; ++nt)
            bf[nt] = *(const bf16x8*)&Bs[b][(wn + nt * 16 + l16) * 32 + quad * 8];
#pragma unroll
        for (int mt = 0; mt < 4; ++mt)
#pragma unroll
            for (int nt = 0; nt < 2; ++nt)
                acc[mt][nt] = __builtin_amdgcn_mfma_f32_16x16x32_bf16(
                    af[mt], bf[nt], acc[mt][nt], 0, 0, 0);
    }
    unsigned short* Pp = P + (size_t)blockIdx.z * MP_ * DIM_;
#pragma unroll
    for (int mt = 0; mt < 4; ++mt) {
#pragma unroll
        for (int nt = 0; nt < 2; ++nt) {
            int gcol = bn + wn + nt * 16 + l16;
#pragma unroll
            for (int r = 0; r < 4; ++r) {
                int grow = bm + wm + mt * 16 + quad * 4 + r;
                if (grow < THW_)
                    Pp[(size_t)grow * DIM_ + gcol] = f2bf(acc[mt][nt][r]);
            }
        }
    }
}

// ---------------------------------------------------------------------------
// K7: out[(t*DIM+n)*HW+hw] = x + b_mlp[n] + sum_s P[s][m][n]
// ---------------------------------------------------------------------------
__global__ __launch_bounds__(256) void reduce_out_kernel(
    const unsigned short* __restrict__ P, const float* __restrict__ x,
    const float* __restrict__ b_mlp, float* __restrict__ out)
{
    __shared__ float tile[32][65];
    int bm = blockIdx.x * 64;
    int bn = blockIdx.y * 32;
    int tid = threadIdx.x;
    int t = bm / HW_;
    int hw0 = bm - t * HW_;
    for (int i = tid; i < 512; i += 256) {
        int ml = i >> 3;
        int n4 = (i & 7) * 4;
        float s0 = 0.f, s1 = 0.f, s2 = 0.f, s3 = 0.f;
#pragma unroll
        for (int sI = 0; sI < SPLITK_; ++sI) {
            const unsigned short* pp =
                P + ((size_t)sI * MP_ + bm + ml) * DIM_ + bn + n4;
            ushort4 u = *(const ushort4*)pp;
            s0 += bf2f(u.x); s1 += bf2f(u.y);
            s2 += bf2f(u.z); s3 += bf2f(u.w);
        }
        tile[n4 + 0][ml] = s0;
        tile[n4 + 1][ml] = s1;
        tile[n4 + 2][ml] = s2;
        tile[n4 + 3][ml] = s3;
    }
    __syncthreads();
    for (int i = tid; i < 512; i += 256) {
        int n = i >> 4;
        int ms = (i & 15) * 4;
        int gn = bn + n;
        size_t base = ((size_t)t * DIM_ + gn) * HW_ + hw0 + ms;
        float bv = b_mlp[gn];
        float4 xv = *(const float4*)(x + base);
        float4 o;
        o.x = xv.x + bv + tile[n][ms + 0];
        o.y = xv.y + bv + tile[n][ms + 1];
        o.z = xv.z + bv + tile[n][ms + 2];
        o.w = xv.w + bv + tile[n][ms + 3];
        *(float4*)(out + base) = o;
    }
}

// ---------------------------------------------------------------------------
extern "C" void kernel_launch(void* const* d_in, const int* in_sizes, int n_in,
                              void* d_out, int out_size, void* d_ws, size_t ws_size,
                              hipStream_t stream) {
    const float* x       = (const float*)d_in[0];
    const float* emb     = (const float*)d_in[1];
    const float* w_mod   = (const float*)d_in[2];
    const float* b_mod   = (const float*)d_in[3];
    const float* qn_w    = (const float*)d_in[4];
    const float* qn_b    = (const float*)d_in[5];
    const float* kn_w    = (const float*)d_in[6];
    const float* kn_b    = (const float*)d_in[7];
    const float* W_fused = (const float*)d_in[8];
    const float* b_fused = (const float*)d_in[9];
    const float* W_out   = (const float*)d_in[10];
    const float* W_mlp   = (const float*)d_in[11];
    const float* b_mlp   = (const float*)d_in[12];
    float* out = (float*)d_out;

    char* w = (char*)d_ws;
    float* mod = (float*)w;            w += (size_t)4608 * 4;
    unsigned short* qkv = (unsigned short*)w;  w += (size_t)THW_ * QK_ * 2;
    unsigned short* vb  = (unsigned short*)w;  w += (size_t)THW_ * DIM_ * 2;
    unsigned short* qb  = (unsigned short*)w;  w += (size_t)HEADS_ * THW_ * DH_ * 2;
    unsigned short* kb  = (unsigned short*)w;  w += (size_t)HEADS_ * THW_ * DH_ * 2;
    unsigned short* h   = (unsigned short*)w;  w += (size_t)MP_ * DIM_ * 2;
    unsigned short* A2  = (unsigned short*)w;  w += (size_t)MP_ * KTOT_ * 2;
    unsigned short* Bt1 = (unsigned short*)w;  w += (size_t)NF_ * DIM_ * 2;
    unsigned short* Bt2 = (unsigned short*)w;  w += (size_t)DIM_ * KTOT_ * 2;
    unsigned short* P   = (unsigned short*)w;  w += (size_t)SPLITK_ * MP_ * DIM_ * 2;

    prep_kernel<<<6948, 256, 0, stream>>>(W_fused, Bt1, W_out, W_mlp, Bt2,
                                          emb, w_mod, b_mod, mod);
    ln_mod_kernel<<<THW_ / 4, 256, 0, stream>>>(x, mod, h);
    gemm1_kernel<<<dim3(NF_ / 64, MP_ / 128), 256, 0, stream>>>(h, Bt1, b_fused, qkv, vb, A2);
    qkln_rope_kernel<<<(HEADS_ * THW_) / 4, 256, 0, stream>>>(qkv, qn_w, qn_b, kn_w, kn_b, qb, kb);
    attn_kernel<<<HEADS_ * 27, 256, 0, stream>>>(qb, kb, vb, A2);
    gemm2_kernel<<<dim3(DIM_ / 64, MP_ / 128, SPLITK_), 256, 0, stream>>>(A2, Bt2, P);
    reduce_out_kernel<<<dim3(THW_ / 64, DIM_ / 32), 256, 0, stream>>>(P, x, b_mlp, out);
}